// Round 4
// baseline (151.675 us; speedup 1.0000x reference)
//
#include <hip/hip_runtime.h>
#include <hip/hip_bf16.h>

// Problem constants
#define NB   4      // batch
#define CCH  3      // channels
#define HW   320    // height == width
#define KS   5      // kernel/stride
#define LP   4096   // patches per batch (64*64)
#define KD   75     // c*k*k
#define NCH  12     // 16B chunks per patch row (96 bf16 = 12 x 8)

typedef __attribute__((ext_vector_type(4))) float f32x4;
typedef __attribute__((ext_vector_type(8))) short bf16x8;

__device__ __forceinline__ ushort f2bf(float v) {
    __hip_bfloat16 h = __float2bfloat16(v);
    return __builtin_bit_cast(ushort, h);
}

// Kernel 1: per-patch sumsq from x (fp32), block-max over 4 patches, one
// device-scope atomicMax per block onto maxbits[b] (float bits, all >= 0).
__global__ __launch_bounds__(256) void norm_kernel(const float* __restrict__ x,
                                                   unsigned* __restrict__ maxbits) {
    int tid  = threadIdx.x;
    int lane = tid & 63;
    int pid  = blockIdx.x * 4 + (tid >> 6);   // 0..16383
    int b    = pid >> 12;
    int pp   = pid & 4095;
    int ph   = pp >> 6, pw = pp & 63;
    const float* xb = x + (size_t)b * (CCH * HW * HW);
    int row0 = ph * KS, col0 = pw * KS;

    float ss = 0.f;
    for (int k = lane; k < KD; k += 64) {
        int c = k / 25, rem = k % 25;
        int ki = rem / 5, kj = rem % 5;
        float v = xb[(c * HW + row0 + ki) * HW + col0 + kj];
        ss += v * v;
    }
    for (int off = 32; off; off >>= 1) ss += __shfl_xor(ss, off, 64);

    __shared__ float sm[4];
    if (lane == 0) sm[tid >> 6] = ss;
    __syncthreads();
    if (tid == 0) {
        float m = fmaxf(fmaxf(sm[0], sm[1]), fmaxf(sm[2], sm[3]));
        atomicMax(maxbits + b, __float_as_uint(m));   // non-negative: bit order == float order
    }
}

// Kernel 2: build bf16 patch matrix in fragment-blocked layout
// p2[b][chunk][row] of 16B (8 bf16): chunk c holds patch cols 8c..8c+7
// (zero-padded past KD=75). Fully written every call (chunks 10,11 = zeros).
__global__ __launch_bounds__(256) void patch_kernel(const float* __restrict__ x,
                                                    ushort* __restrict__ p2) {
    int tid = threadIdx.x;
    int r   = blockIdx.x * 256 + tid;    // patch row 0..4095
    int c   = blockIdx.y;                // chunk 0..11
    int b   = blockIdx.z;
    int ph = r >> 6, pw = r & 63;
    const float* xb = x + (size_t)b * (CCH * HW * HW);

    bf16x8 v = {};
    if (c < 10) {
        #pragma unroll
        for (int j = 0; j < 8; ++j) {
            int k = c * 8 + j;
            float f = 0.f;
            if (k < KD) {
                int ch = k / 25, rem = k % 25;
                int ki = rem / 5, kj = rem % 5;
                f = xb[(ch * HW + ph * KS + ki) * HW + pw * KS + kj];
            }
            v[j] = (short)f2bf(f);
        }
    }
    *(bf16x8*)&p2[((size_t)(b * NCH + c) * LP + r) * 8] = v;
}

// Kernel 3: per batch C = sigmoid((P P^T) / sqrt(max_sumsq)), 128x128 tile
// per block, NO LDS: MFMA fragments read directly from the blocked patch
// matrix (coalesced 256B runs, L2-resident). 4 waves 2x2, each 64x64 out.
// Epilogue stores the TRANSPOSE of each fragment (C symmetric, MFMA k-order
// identical for (i,j)/(j,i) -> bit-identical) as nontemporal float4.
__global__ __launch_bounds__(256) void gemm_kernel(const ushort* __restrict__ p2,
                                                   const unsigned* __restrict__ maxbits,
                                                   float* __restrict__ out) {
    int b  = blockIdx.z;
    int tr = blockIdx.y;   // tile row (p-index / 128)
    int tc = blockIdx.x;   // tile col (q-index / 128)
    int tid = threadIdx.x;
    int lane = tid & 63;
    int w  = tid >> 6;
    int wr = w >> 1, wc = w & 1;        // 2x2 wave grid, each wave 64x64 out
    int lrow = lane & 15;
    int lch  = lane >> 4;               // chunk offset within a k-step (0..3)

    const ushort* pb = p2 + (size_t)b * NCH * LP * 8;
    int ar0 = tr * 128 + wr * 64;
    int br0 = tc * 128 + wc * 64;

    f32x4 acc[4][4] = {};
    #pragma unroll
    for (int ks = 0; ks < 3; ++ks) {
        const ushort* pk = pb + (size_t)(ks * 4 + lch) * LP * 8;  // chunk plane
        bf16x8 af[4], bfr[4];
        #pragma unroll
        for (int m = 0; m < 4; ++m)
            af[m] = *(const bf16x8*)&pk[(size_t)(ar0 + m * 16 + lrow) * 8];
        #pragma unroll
        for (int n = 0; n < 4; ++n)
            bfr[n] = *(const bf16x8*)&pk[(size_t)(br0 + n * 16 + lrow) * 8];
        #pragma unroll
        for (int m = 0; m < 4; ++m)
            #pragma unroll
            for (int n = 0; n < 4; ++n)
                acc[m][n] = __builtin_amdgcn_mfma_f32_16x16x32_bf16(af[m], bfr[n], acc[m][n], 0, 0, 0);
    }

    float inv = 1.0f / sqrtf(__uint_as_float(maxbits[b]));
    float* ob = out + (size_t)b * LP * LP;
    #pragma unroll
    for (int m = 0; m < 4; ++m) {
        #pragma unroll
        for (int n = 0; n < 4; ++n) {
            // C/D layout: col=lane&15, row=(lane>>4)*4+reg. Store transposed:
            // out row = GEMM col, out col = GEMM row (4 consecutive -> float4).
            int trow = tc * 128 + wc * 64 + n * 16 + (lane & 15);
            int tcol = ar0 + m * 16 + (lane >> 4) * 4;
            f32x4 v;
            #pragma unroll
            for (int r = 0; r < 4; ++r) {
                float s = acc[m][n][r] * inv;
                v[r] = 1.0f / (1.0f + __expf(-s));
            }
            __builtin_nontemporal_store(v, (f32x4*)&ob[(size_t)trow * LP + tcol]);
        }
    }
}

extern "C" void kernel_launch(void* const* d_in, const int* in_sizes, int n_in,
                              void* d_out, int out_size, void* d_ws, size_t ws_size,
                              hipStream_t stream) {
    const float* x = (const float*)d_in[0];
    float* out = (float*)d_out;

    // ws layout: p2 bf16 blocked [NB][12][4096][8] (3.15 MB), then maxbits[4].
    ushort* p2 = (ushort*)d_ws;
    unsigned* maxbits = (unsigned*)((char*)d_ws + (size_t)NB * NCH * LP * 16);

    hipMemsetAsync(maxbits, 0, NB * sizeof(unsigned), stream);   // capture-legal
    norm_kernel<<<(NB * LP) / 4, 256, 0, stream>>>(x, maxbits);
    patch_kernel<<<dim3(LP / 256, NCH, NB), 256, 0, stream>>>(x, p2);
    gemm_kernel<<<dim3(32, 32, NB), 256, 0, stream>>>(p2, maxbits, out);
}

// Round 5
// 111.523 us; speedup vs baseline: 1.3600x; 1.3600x over previous
//
#include <hip/hip_runtime.h>
#include <hip/hip_bf16.h>

// Problem constants
#define NB   4      // batch
#define CCH  3      // channels
#define HW   320    // height == width
#define KS   5      // kernel/stride
#define LP   4096   // patches per batch (64*64)
#define KD   75     // c*k*k
#define NCH  12     // 16B chunks per patch row (96 bf16 = 12 x 8)

typedef __attribute__((ext_vector_type(4))) float f32x4;
typedef __attribute__((ext_vector_type(8))) short bf16x8;

__device__ __forceinline__ ushort f2bf(float v) {
    __hip_bfloat16 h = __float2bfloat16(v);
    return __builtin_bit_cast(ushort, h);
}

// Kernel 1: per-patch sumsq from x (fp32), block-max over 4 patches, one
// device-scope atomicMax per block onto maxbits[b] (float bits, all >= 0).
__global__ __launch_bounds__(256) void norm_kernel(const float* __restrict__ x,
                                                   unsigned* __restrict__ maxbits) {
    int tid  = threadIdx.x;
    int lane = tid & 63;
    int pid  = blockIdx.x * 4 + (tid >> 6);   // 0..16383
    int b    = pid >> 12;
    int pp   = pid & 4095;
    int ph   = pp >> 6, pw = pp & 63;
    const float* xb = x + (size_t)b * (CCH * HW * HW);
    int row0 = ph * KS, col0 = pw * KS;

    float ss = 0.f;
    for (int k = lane; k < KD; k += 64) {
        int c = k / 25, rem = k % 25;
        int ki = rem / 5, kj = rem % 5;
        float v = xb[(c * HW + row0 + ki) * HW + col0 + kj];
        ss += v * v;
    }
    for (int off = 32; off; off >>= 1) ss += __shfl_xor(ss, off, 64);

    __shared__ float sm[4];
    if (lane == 0) sm[tid >> 6] = ss;
    __syncthreads();
    if (tid == 0) {
        float m = fmaxf(fmaxf(sm[0], sm[1]), fmaxf(sm[2], sm[3]));
        atomicMax(maxbits + b, __float_as_uint(m));   // non-negative: bit order == float order
    }
}

// Kernel 2: build bf16 patch matrix in fragment-blocked layout
// p2[b][chunk][row] of 16B (8 bf16): chunk c holds patch cols 8c..8c+7
// (zero-padded past KD=75). Fully written every call (chunks 10,11 = zeros).
__global__ __launch_bounds__(256) void patch_kernel(const float* __restrict__ x,
                                                    ushort* __restrict__ p2) {
    int tid = threadIdx.x;
    int r   = blockIdx.x * 256 + tid;    // patch row 0..4095
    int c   = blockIdx.y;                // chunk 0..11
    int b   = blockIdx.z;
    int ph = r >> 6, pw = r & 63;
    const float* xb = x + (size_t)b * (CCH * HW * HW);

    bf16x8 v = {};
    if (c < 10) {
        #pragma unroll
        for (int j = 0; j < 8; ++j) {
            int k = c * 8 + j;
            float f = 0.f;
            if (k < KD) {
                int ch = k / 25, rem = k % 25;
                int ki = rem / 5, kj = rem % 5;
                f = xb[(ch * HW + ph * KS + ki) * HW + pw * KS + kj];
            }
            v[j] = (short)f2bf(f);
        }
    }
    *(bf16x8*)&p2[((size_t)(b * NCH + c) * LP + r) * 8] = v;
}

// Kernel 3: per batch C = sigmoid((P P^T) / sqrt(max_sumsq)), 128x128 tile
// per block, fragments read directly from blocked p2 (coalesced, L2-resident).
// 4 waves 2x2, each 64x64 out. Epilogue: per-wave LDS restage (4KB, swizzled,
// no barriers) so each global store instruction writes 256B full-line runs
// (16 lanes x 16B per output row, 4 rows per 1KB store) -> no read-for-
// ownership on partial lines. Output stored transposed (C symmetric, MFMA
// k-order identical for (i,j)/(j,i) -> bit-identical).
__global__ __launch_bounds__(256) void gemm_kernel(const ushort* __restrict__ p2,
                                                   const unsigned* __restrict__ maxbits,
                                                   float* __restrict__ out) {
    __shared__ float W[4][16][64];     // per-wave restage buffer (swizzled slots)

    int b  = blockIdx.z;
    int tr = blockIdx.y;   // tile row (i-index / 128)
    int tc = blockIdx.x;   // tile col (j-index / 128)
    int tid = threadIdx.x;
    int lane = tid & 63;
    int w  = tid >> 6;
    int wr = w >> 1, wc = w & 1;        // 2x2 wave grid, each wave 64x64 out
    int lrow = lane & 15;
    int lch  = lane >> 4;               // quarter index 0..3

    const ushort* pb = p2 + (size_t)b * NCH * LP * 8;
    int ar0 = tr * 128 + wr * 64;       // i rows (A fragments)
    int br0 = tc * 128 + wc * 64;       // j rows (B fragments)

    f32x4 acc[4][4] = {};
    #pragma unroll
    for (int ks = 0; ks < 3; ++ks) {
        const ushort* pk = pb + (size_t)(ks * 4 + lch) * LP * 8;  // chunk plane
        bf16x8 af[4], bfr[4];
        #pragma unroll
        for (int m = 0; m < 4; ++m)
            af[m] = *(const bf16x8*)&pk[(size_t)(ar0 + m * 16 + lrow) * 8];
        #pragma unroll
        for (int n = 0; n < 4; ++n)
            bfr[n] = *(const bf16x8*)&pk[(size_t)(br0 + n * 16 + lrow) * 8];
        #pragma unroll
        for (int m = 0; m < 4; ++m)
            #pragma unroll
            for (int n = 0; n < 4; ++n)
                acc[m][n] = __builtin_amdgcn_mfma_f32_16x16x32_bf16(af[m], bfr[n], acc[m][n], 0, 0, 0);
    }

    float inv = 1.0f / sqrtf(__uint_as_float(maxbits[b]));
    float* ob = out + (size_t)b * LP * LP;
    float* Wp = &W[w][0][0];

    // Out rows j = br0 + n*16 + (lane&15); out cols i = ar0 + m*16 + lch*4 + reg.
    // Stream one n-stripe (16 j-rows x 64 i-cols) at a time through LDS.
    #pragma unroll
    for (int n = 0; n < 4; ++n) {
        // scatter fragments into swizzled LDS: slot' = slot ^ row
        #pragma unroll
        for (int m = 0; m < 4; ++m) {
            int slot = (m * 4 + lch) ^ lrow;       // 16B slot 0..15, swizzled
            f32x4 v;
            #pragma unroll
            for (int r = 0; r < 4; ++r) {
                float s = acc[m][n][r] * inv;
                v[r] = 1.0f / (1.0f + __expf(-s));
            }
            *(f32x4*)&Wp[lrow * 64 + slot * 4] = v;
        }
        // gather rows linearly and store 256B full-line runs
        #pragma unroll
        for (int k = 0; k < 4; ++k) {
            int row  = k * 4 + lch;                // local j-row 0..15
            int slot = lrow ^ row;                 // inverse swizzle
            f32x4 v = *(const f32x4*)&Wp[row * 64 + slot * 4];
            int j = br0 + n * 16 + row;
            int i = ar0 + lrow * 4;
            *(f32x4*)&ob[(size_t)j * LP + i] = v;
        }
    }
}

extern "C" void kernel_launch(void* const* d_in, const int* in_sizes, int n_in,
                              void* d_out, int out_size, void* d_ws, size_t ws_size,
                              hipStream_t stream) {
    const float* x = (const float*)d_in[0];
    float* out = (float*)d_out;

    // ws layout: p2 bf16 blocked [NB][12][4096][8] (3.15 MB), then maxbits[4].
    ushort* p2 = (ushort*)d_ws;
    unsigned* maxbits = (unsigned*)((char*)d_ws + (size_t)NB * NCH * LP * 16);

    hipMemsetAsync(maxbits, 0, NB * sizeof(unsigned), stream);   // capture-legal
    norm_kernel<<<(NB * LP) / 4, 256, 0, stream>>>(x, maxbits);
    patch_kernel<<<dim3(LP / 256, NCH, NB), 256, 0, stream>>>(x, p2);
    gemm_kernel<<<dim3(32, 32, NB), 256, 0, stream>>>(p2, maxbits, out);
}